// Round 4
// baseline (78.799 us; speedup 1.0000x reference)
//
#include <hip/hip_runtime.h>
#include <math.h>

#define BLK 256
// tile = 256 w-chunks = 1024 points = 768 x/g float4-chunks

// ---------------- Pass 1: raw moment reduction (one tile per block, churn) ----------------
// accumulators: a[0]=sum w; a[1..3]=sum w*x; a[4..6]=sum w*g; a[7..15]=sum w*x_i*g_j
__global__ __launch_bounds__(BLK) void wra_reduce(
    const float* __restrict__ x, const float* __restrict__ g,
    const float* __restrict__ w, float* __restrict__ partials,
    int n4, int n, int ntiles)
{
    __shared__ float4 xs[768];
    __shared__ float4 gs[768];

    float a[16];
#pragma unroll
    for (int i = 0; i < 16; ++i) a[i] = 0.f;

    const float4* __restrict__ x4 = (const float4*)x;
    const float4* __restrict__ g4 = (const float4*)g;
    const float4* __restrict__ w4 = (const float4*)w;

    const int tid = threadIdx.x;
    const int totc = 3 * n4;   // total x/g float4 chunks
    const float4 z4 = make_float4(0.f, 0.f, 0.f, 0.f);

    // normally gridDim.x == ntiles (single-shot); loop is a ws-size fallback
    for (int t = blockIdx.x; t < ntiles; t += gridDim.x) {
        if (t != (int)blockIdx.x) __syncthreads();   // protect LDS reuse (uniform branch)

        const int cb = t * 768;
        // stage x,g: lane-contiguous float4 loads -> LDS
        if (cb + 768 <= totc) {
#pragma unroll
            for (int k = 0; k < 3; ++k) {
                int c = cb + tid + 256 * k;
                xs[tid + 256 * k] = x4[c];
                gs[tid + 256 * k] = g4[c];
            }
        } else {
#pragma unroll
            for (int k = 0; k < 3; ++k) {
                int c = cb + tid + 256 * k;
                float4 xv = z4, gv = z4;
                if (c < totc) { xv = x4[c]; gv = g4[c]; }
                xs[tid + 256 * k] = xv;
                gs[tid + 256 * k] = gv;
            }
        }
        // w is lane-contiguous already: straight to register
        int wc = t * 256 + tid;
        float4 wv = (wc < n4) ? w4[wc] : z4;
        __syncthreads();

        float4 xa = xs[3 * tid + 0], xb = xs[3 * tid + 1], xc = xs[3 * tid + 2];
        float4 ga = gs[3 * tid + 0], gb = gs[3 * tid + 1], gc = gs[3 * tid + 2];

        float pxc[4] = {xa.x, xa.w, xb.z, xc.y};
        float pyc[4] = {xa.y, xb.x, xb.w, xc.z};
        float pzc[4] = {xa.z, xb.y, xc.x, xc.w};
        float qxc[4] = {ga.x, ga.w, gb.z, gc.y};
        float qyc[4] = {ga.y, gb.x, gb.w, gc.z};
        float qzc[4] = {ga.z, gb.y, gc.x, gc.w};
        float wt[4]  = {wv.x, wv.y, wv.z, wv.w};
#pragma unroll
        for (int k = 0; k < 4; ++k) {
            float wk = wt[k];
            float wpx = wk * pxc[k], wpy = wk * pyc[k], wpz = wk * pzc[k];
            a[0] += wk;
            a[1] += wpx;          a[2] += wpy;          a[3] += wpz;
            a[4] += wk * qxc[k];  a[5] += wk * qyc[k];  a[6] += wk * qzc[k];
            a[7]  += wpx * qxc[k]; a[8]  += wpx * qyc[k]; a[9]  += wpx * qzc[k];
            a[10] += wpy * qxc[k]; a[11] += wpy * qyc[k]; a[12] += wpy * qzc[k];
            a[13] += wpz * qxc[k]; a[14] += wpz * qyc[k]; a[15] += wpz * qzc[k];
        }
    }

    // scalar tail (n not divisible by 4) — block 0 / thread 0
    if (blockIdx.x == 0 && tid == 0) {
        for (int r = n4 * 4; r < n; ++r) {
            float wk = w[r];
            float X = x[3 * r], Y = x[3 * r + 1], Z = x[3 * r + 2];
            float Gx = g[3 * r], Gy = g[3 * r + 1], Gz = g[3 * r + 2];
            float wpx = wk * X, wpy = wk * Y, wpz = wk * Z;
            a[0] += wk;
            a[1] += wpx;      a[2] += wpy;      a[3] += wpz;
            a[4] += wk * Gx;  a[5] += wk * Gy;  a[6] += wk * Gz;
            a[7]  += wpx * Gx; a[8]  += wpx * Gy; a[9]  += wpx * Gz;
            a[10] += wpy * Gx; a[11] += wpy * Gy; a[12] += wpy * Gz;
            a[13] += wpz * Gx; a[14] += wpz * Gy; a[15] += wpz * Gz;
        }
    }

    // wave (64-lane) shuffle reduction per component
#pragma unroll
    for (int i = 0; i < 16; ++i) {
        float v = a[i];
        for (int off = 32; off > 0; off >>= 1) v += __shfl_down(v, off, 64);
        a[i] = v;
    }
    __shared__ float red[4][16];
    int lane = tid & 63;
    int wid  = tid >> 6;
    __syncthreads();   // LDS reuse vs main loop (red aliases nothing, but order waves)
    if (lane == 0) {
#pragma unroll
        for (int i = 0; i < 16; ++i) red[wid][i] = a[i];
    }
    __syncthreads();
    if (tid < 16) {
        float s = red[0][tid] + red[1][tid] + red[2][tid] + red[3][tid];
        partials[blockIdx.x * 16 + tid] = s;
    }
}

// ---------------- Pass 2: final reduce + 3x3 SVD solve (1 wave) ----------------
__global__ __launch_bounds__(64) void wra_solve(
    const float* __restrict__ partials, int nb, float* __restrict__ rt)
{
    int lane = threadIdx.x;
    double acc[16];
#pragma unroll
    for (int i = 0; i < 16; ++i) acc[i] = 0.0;
    for (int b = lane; b < nb; b += 64) {
#pragma unroll
        for (int i = 0; i < 16; ++i) acc[i] += (double)partials[b * 16 + i];
    }
#pragma unroll
    for (int i = 0; i < 16; ++i) {
        double v = acc[i];
        for (int off = 32; off > 0; off >>= 1) v += __shfl_down(v, off, 64);
        acc[i] = v;
    }
    if (lane != 0) return;

    double Sw = acc[0];
    double Sx[3] = {acc[1], acc[2], acc[3]};
    double Sg[3] = {acc[4], acc[5], acc[6]};
    double Hr[3][3];
    for (int i = 0; i < 3; ++i)
        for (int j = 0; j < 3; ++j) Hr[i][j] = acc[7 + i * 3 + j];

    double W = Sw + 1e-8;
    double mu[3], mg[3];
    for (int i = 0; i < 3; ++i) { mu[i] = Sx[i] / W; mg[i] = Sg[i] / W; }

    double H[3][3];
    for (int i = 0; i < 3; ++i)
        for (int j = 0; j < 3; ++j)
            H[i][j] = Hr[i][j] - mu[i] * Sg[j] - mg[j] * Sx[i] + mu[i] * mg[j] * Sw;

    double A[3][3];
    for (int i = 0; i < 3; ++i)
        for (int j = 0; j < 3; ++j) {
            double s = 0.0;
            for (int k = 0; k < 3; ++k) s += H[k][i] * H[k][j];
            A[i][j] = s;
        }

    double V[3][3] = {{1,0,0},{0,1,0},{0,0,1}};
    const int pr[3] = {0, 0, 1}, qr[3] = {1, 2, 2};
    for (int sweep = 0; sweep < 25; ++sweep) {
        for (int r = 0; r < 3; ++r) {
            int p = pr[r], q = qr[r];
            double apq = A[p][q];
            if (fabs(apq) < 1e-30) continue;
            double tau = (A[q][q] - A[p][p]) / (2.0 * apq);
            double t = (tau >= 0 ? 1.0 : -1.0) / (fabs(tau) + sqrt(1.0 + tau * tau));
            double c = 1.0 / sqrt(1.0 + t * t), s = t * c;
            for (int k = 0; k < 3; ++k) {
                double akp = A[k][p], akq = A[k][q];
                A[k][p] = c * akp - s * akq;
                A[k][q] = s * akp + c * akq;
            }
            for (int k = 0; k < 3; ++k) {
                double apk = A[p][k], aqk = A[q][k];
                A[p][k] = c * apk - s * aqk;
                A[q][k] = s * apk + c * aqk;
            }
            for (int k = 0; k < 3; ++k) {
                double vkp = V[k][p], vkq = V[k][q];
                V[k][p] = c * vkp - s * vkq;
                V[k][q] = s * vkp + c * vkq;
            }
        }
    }
    double lam[3] = {A[0][0], A[1][1], A[2][2]};

    int idx[3] = {0, 1, 2};
    if (lam[idx[0]] < lam[idx[1]]) { int t = idx[0]; idx[0] = idx[1]; idx[1] = t; }
    if (lam[idx[1]] < lam[idx[2]]) { int t = idx[1]; idx[1] = idx[2]; idx[2] = t; }
    if (lam[idx[0]] < lam[idx[1]]) { int t = idx[0]; idx[0] = idx[1]; idx[1] = t; }

    double Vs[3][3], U[3][3];
    for (int k = 0; k < 3; ++k) {
        int c0 = idx[k];
        double l = lam[c0] > 1e-30 ? lam[c0] : 1e-30;
        double inv = 1.0 / sqrt(l);
        for (int i = 0; i < 3; ++i) Vs[i][k] = V[i][c0];
        for (int i = 0; i < 3; ++i) {
            double s = 0.0;
            for (int j = 0; j < 3; ++j) s += H[i][j] * Vs[j][k];
            U[i][k] = s * inv;
        }
    }

    double detH = H[0][0] * (H[1][1] * H[2][2] - H[1][2] * H[2][1])
                - H[0][1] * (H[1][0] * H[2][2] - H[1][2] * H[2][0])
                + H[0][2] * (H[1][0] * H[2][1] - H[1][1] * H[2][0]);
    double d = (detH < 0.0) ? -1.0 : 1.0;

    double R[3][3];
    for (int i = 0; i < 3; ++i)
        for (int j = 0; j < 3; ++j)
            R[i][j] = U[i][0] * Vs[j][0] + U[i][1] * Vs[j][1] + d * U[i][2] * Vs[j][2];

    double tv[3];
    for (int i = 0; i < 3; ++i)
        tv[i] = mu[i] - (R[i][0] * mg[0] + R[i][1] * mg[1] + R[i][2] * mg[2]);

    for (int i = 0; i < 3; ++i)
        for (int j = 0; j < 3; ++j) rt[i * 3 + j] = (float)R[i][j];
    for (int i = 0; i < 3; ++i) rt[9 + i] = (float)tv[i];
}

// ---------------- Pass 3: apply out = R * g + t (one tile per block) ----------------
__global__ __launch_bounds__(BLK) void wra_apply(
    const float* __restrict__ g, const float* __restrict__ rt,
    float* __restrict__ out, int n4, int n, int ntiles)
{
    __shared__ float4 buf[768];

    float R00 = rt[0], R01 = rt[1], R02 = rt[2];
    float R10 = rt[3], R11 = rt[4], R12 = rt[5];
    float R20 = rt[6], R21 = rt[7], R22 = rt[8];
    float t0 = rt[9], t1 = rt[10], t2 = rt[11];

    const float4* __restrict__ g4 = (const float4*)g;
    float4* __restrict__ o4 = (float4*)out;

    const int tid = threadIdx.x;
    const int totc = 3 * n4;

    for (int t = blockIdx.x; t < ntiles; t += gridDim.x) {
        if (t != (int)blockIdx.x) __syncthreads();   // LDS reuse guard (fallback path)

        const int cb = t * 768;
#pragma unroll
        for (int k = 0; k < 3; ++k) {
            int c = cb + tid + 256 * k;
            if (c < totc) buf[tid + 256 * k] = g4[c];
        }
        __syncthreads();

        float4 ga = buf[3 * tid + 0], gb = buf[3 * tid + 1], gc = buf[3 * tid + 2];
        float qx0 = ga.x, qy0 = ga.y, qz0 = ga.z;
        float qx1 = ga.w, qy1 = gb.x, qz1 = gb.y;
        float qx2 = gb.z, qy2 = gb.w, qz2 = gc.x;
        float qx3 = gc.y, qy3 = gc.z, qz3 = gc.w;

        float ox0 = R00*qx0 + R01*qy0 + R02*qz0 + t0;
        float oy0 = R10*qx0 + R11*qy0 + R12*qz0 + t1;
        float oz0 = R20*qx0 + R21*qy0 + R22*qz0 + t2;
        float ox1 = R00*qx1 + R01*qy1 + R02*qz1 + t0;
        float oy1 = R10*qx1 + R11*qy1 + R12*qz1 + t1;
        float oz1 = R20*qx1 + R21*qy1 + R22*qz1 + t2;
        float ox2 = R00*qx2 + R01*qy2 + R02*qz2 + t0;
        float oy2 = R10*qx2 + R11*qy2 + R12*qz2 + t1;
        float oz2 = R20*qx2 + R21*qy2 + R22*qz2 + t2;
        float ox3 = R00*qx3 + R01*qy3 + R02*qz3 + t0;
        float oy3 = R10*qx3 + R11*qy3 + R12*qz3 + t1;
        float oz3 = R20*qx3 + R21*qy3 + R22*qz3 + t2;

        // write back to own slots (each thread touches only its own 3 chunks)
        buf[3 * tid + 0] = make_float4(ox0, oy0, oz0, ox1);
        buf[3 * tid + 1] = make_float4(oy1, oz1, ox2, oy2);
        buf[3 * tid + 2] = make_float4(oz2, ox3, oy3, oz3);
        __syncthreads();

#pragma unroll
        for (int k = 0; k < 3; ++k) {
            int c = cb + tid + 256 * k;
            if (c < totc) o4[c] = buf[tid + 256 * k];
        }
    }

    // scalar tail
    int gtid = blockIdx.x * blockDim.x + threadIdx.x;
    int gstr = gridDim.x * blockDim.x;
    for (int r = n4 * 4 + gtid; r < n; r += gstr) {
        float Gx = g[3 * r], Gy = g[3 * r + 1], Gz = g[3 * r + 2];
        out[3 * r + 0] = R00 * Gx + R01 * Gy + R02 * Gz + t0;
        out[3 * r + 1] = R10 * Gx + R11 * Gy + R12 * Gz + t1;
        out[3 * r + 2] = R20 * Gx + R21 * Gy + R22 * Gz + t2;
    }
}

extern "C" void kernel_launch(void* const* d_in, const int* in_sizes, int n_in,
                              void* d_out, int out_size, void* d_ws, size_t ws_size,
                              hipStream_t stream)
{
    const float* x = (const float*)d_in[0];
    const float* g = (const float*)d_in[1];
    const float* w = (const float*)d_in[2];
    float* out = (float*)d_out;

    int n = in_sizes[2];      // number of points
    int n4 = n / 4;           // w float4-chunks
    int ntiles = (n4 + 255) / 256;
    if (ntiles < 1) ntiles = 1;

    // one tile per block (block churn keeps loads in flight); clamp by ws size
    int nbr = ntiles;
    int maxnb = (int)((ws_size / sizeof(float) - 12) / 16);
    if (nbr > maxnb) nbr = maxnb;
    if (nbr < 1) nbr = 1;

    float* partials = (float*)d_ws;
    float* rt = partials + (size_t)nbr * 16;

    wra_reduce<<<nbr, BLK, 0, stream>>>(x, g, w, partials, n4, n, ntiles);
    wra_solve<<<1, 64, 0, stream>>>(partials, nbr, rt);

    wra_apply<<<ntiles, BLK, 0, stream>>>(g, rt, out, n4, n, ntiles);
}

// Round 5
// 61.666 us; speedup vs baseline: 1.2778x; 1.2778x over previous
//
#include <hip/hip_runtime.h>
#include <math.h>

typedef float f32x4 __attribute__((ext_vector_type(4)));

#define BLK 256

__device__ __forceinline__ void accum4(
    float a[16], f32x4 xa, f32x4 xb, f32x4 xc,
    f32x4 ga, f32x4 gb, f32x4 gc, f32x4 wv)
{
    float px[4] = {xa.x, xa.w, xb.z, xc.y};
    float py[4] = {xa.y, xb.x, xb.w, xc.z};
    float pz[4] = {xa.z, xb.y, xc.x, xc.w};
    float qx[4] = {ga.x, ga.w, gb.z, gc.y};
    float qy[4] = {ga.y, gb.x, gb.w, gc.z};
    float qz[4] = {ga.z, gb.y, gc.x, gc.w};
    float wt[4] = {wv.x, wv.y, wv.z, wv.w};
#pragma unroll
    for (int k = 0; k < 4; ++k) {
        float wk = wt[k];
        float wpx = wk * px[k], wpy = wk * py[k], wpz = wk * pz[k];
        a[0] += wk;
        a[1] += wpx;         a[2] += wpy;         a[3] += wpz;
        a[4] += wk * qx[k];  a[5] += wk * qy[k];  a[6] += wk * qz[k];
        a[7]  += wpx * qx[k]; a[8]  += wpx * qy[k]; a[9]  += wpx * qz[k];
        a[10] += wpy * qx[k]; a[11] += wpy * qy[k]; a[12] += wpy * qz[k];
        a[13] += wpz * qx[k]; a[14] += wpz * qy[k]; a[15] += wpz * qz[k];
    }
}

// ---------------- Pass 1: raw moment reduction (direct regs, nt loads, 2x unroll) ----------------
// accumulators: a[0]=sum w; a[1..3]=sum w*x; a[4..6]=sum w*g; a[7..15]=sum w*x_i*g_j
__global__ __launch_bounds__(BLK) void wra_reduce(
    const float* __restrict__ x, const float* __restrict__ g,
    const float* __restrict__ w, float* __restrict__ partials,
    int n4, int n)
{
    float a[16];
#pragma unroll
    for (int i = 0; i < 16; ++i) a[i] = 0.f;

    const f32x4* __restrict__ x4 = (const f32x4*)x;
    const f32x4* __restrict__ g4 = (const f32x4*)g;
    const f32x4* __restrict__ w4 = (const f32x4*)w;

    int tid = blockIdx.x * blockDim.x + threadIdx.x;
    int stride = gridDim.x * blockDim.x;

    int i = tid;
    // 2x-unrolled main loop: 14 loads in flight before any compute
    for (; i + stride < n4; i += 2 * stride) {
        int j = i + stride;
        f32x4 xa0 = __builtin_nontemporal_load(&x4[3*i+0]);
        f32x4 xb0 = __builtin_nontemporal_load(&x4[3*i+1]);
        f32x4 xc0 = __builtin_nontemporal_load(&x4[3*i+2]);
        f32x4 ga0 = g4[3*i+0];
        f32x4 gb0 = g4[3*i+1];
        f32x4 gc0 = g4[3*i+2];
        f32x4 wv0 = __builtin_nontemporal_load(&w4[i]);
        f32x4 xa1 = __builtin_nontemporal_load(&x4[3*j+0]);
        f32x4 xb1 = __builtin_nontemporal_load(&x4[3*j+1]);
        f32x4 xc1 = __builtin_nontemporal_load(&x4[3*j+2]);
        f32x4 ga1 = g4[3*j+0];
        f32x4 gb1 = g4[3*j+1];
        f32x4 gc1 = g4[3*j+2];
        f32x4 wv1 = __builtin_nontemporal_load(&w4[j]);
        accum4(a, xa0, xb0, xc0, ga0, gb0, gc0, wv0);
        accum4(a, xa1, xb1, xc1, ga1, gb1, gc1, wv1);
    }
    for (; i < n4; i += stride) {
        f32x4 xa = __builtin_nontemporal_load(&x4[3*i+0]);
        f32x4 xb = __builtin_nontemporal_load(&x4[3*i+1]);
        f32x4 xc = __builtin_nontemporal_load(&x4[3*i+2]);
        f32x4 ga = g4[3*i+0];
        f32x4 gb = g4[3*i+1];
        f32x4 gc = g4[3*i+2];
        f32x4 wv = __builtin_nontemporal_load(&w4[i]);
        accum4(a, xa, xb, xc, ga, gb, gc, wv);
    }

    // scalar tail (n not divisible by 4) — global thread 0
    if (blockIdx.x == 0 && threadIdx.x == 0) {
        for (int r = n4 * 4; r < n; ++r) {
            float wk = w[r];
            float X = x[3*r], Y = x[3*r+1], Z = x[3*r+2];
            float Gx = g[3*r], Gy = g[3*r+1], Gz = g[3*r+2];
            float wpx = wk * X, wpy = wk * Y, wpz = wk * Z;
            a[0] += wk;
            a[1] += wpx;      a[2] += wpy;      a[3] += wpz;
            a[4] += wk * Gx;  a[5] += wk * Gy;  a[6] += wk * Gz;
            a[7]  += wpx * Gx; a[8]  += wpx * Gy; a[9]  += wpx * Gz;
            a[10] += wpy * Gx; a[11] += wpy * Gy; a[12] += wpy * Gz;
            a[13] += wpz * Gx; a[14] += wpz * Gy; a[15] += wpz * Gz;
        }
    }

    // wave (64-lane) shuffle reduction per component
#pragma unroll
    for (int i2 = 0; i2 < 16; ++i2) {
        float v = a[i2];
        for (int off = 32; off > 0; off >>= 1) v += __shfl_down(v, off, 64);
        a[i2] = v;
    }
    __shared__ float red[4][16];
    int lane = threadIdx.x & 63;
    int wid  = threadIdx.x >> 6;
    if (lane == 0) {
#pragma unroll
        for (int i2 = 0; i2 < 16; ++i2) red[wid][i2] = a[i2];
    }
    __syncthreads();
    if (threadIdx.x < 16) {
        float s = red[0][threadIdx.x] + red[1][threadIdx.x]
                + red[2][threadIdx.x] + red[3][threadIdx.x];
        partials[blockIdx.x * 16 + threadIdx.x] = s;
    }
}

// ---------------- Pass 2: final reduce + 3x3 SVD solve (1 wave) ----------------
__global__ __launch_bounds__(64) void wra_solve(
    const float* __restrict__ partials, int nb, float* __restrict__ rt)
{
    int lane = threadIdx.x;
    double acc[16];
#pragma unroll
    for (int i = 0; i < 16; ++i) acc[i] = 0.0;
    for (int b = lane; b < nb; b += 64) {
#pragma unroll
        for (int i = 0; i < 16; ++i) acc[i] += (double)partials[b * 16 + i];
    }
#pragma unroll
    for (int i = 0; i < 16; ++i) {
        double v = acc[i];
        for (int off = 32; off > 0; off >>= 1) v += __shfl_down(v, off, 64);
        acc[i] = v;
    }
    if (lane != 0) return;

    double Sw = acc[0];
    double Sx[3] = {acc[1], acc[2], acc[3]};
    double Sg[3] = {acc[4], acc[5], acc[6]};
    double Hr[3][3];
    for (int i = 0; i < 3; ++i)
        for (int j = 0; j < 3; ++j) Hr[i][j] = acc[7 + i * 3 + j];

    double W = Sw + 1e-8;
    double mu[3], mg[3];
    for (int i = 0; i < 3; ++i) { mu[i] = Sx[i] / W; mg[i] = Sg[i] / W; }

    double H[3][3];
    for (int i = 0; i < 3; ++i)
        for (int j = 0; j < 3; ++j)
            H[i][j] = Hr[i][j] - mu[i] * Sg[j] - mg[j] * Sx[i] + mu[i] * mg[j] * Sw;

    double A[3][3];
    for (int i = 0; i < 3; ++i)
        for (int j = 0; j < 3; ++j) {
            double s = 0.0;
            for (int k = 0; k < 3; ++k) s += H[k][i] * H[k][j];
            A[i][j] = s;
        }

    double V[3][3] = {{1,0,0},{0,1,0},{0,0,1}};
    const int pr[3] = {0, 0, 1}, qr[3] = {1, 2, 2};
    for (int sweep = 0; sweep < 25; ++sweep) {
        for (int r = 0; r < 3; ++r) {
            int p = pr[r], q = qr[r];
            double apq = A[p][q];
            if (fabs(apq) < 1e-30) continue;
            double tau = (A[q][q] - A[p][p]) / (2.0 * apq);
            double t = (tau >= 0 ? 1.0 : -1.0) / (fabs(tau) + sqrt(1.0 + tau * tau));
            double c = 1.0 / sqrt(1.0 + t * t), s = t * c;
            for (int k = 0; k < 3; ++k) {
                double akp = A[k][p], akq = A[k][q];
                A[k][p] = c * akp - s * akq;
                A[k][q] = s * akp + c * akq;
            }
            for (int k = 0; k < 3; ++k) {
                double apk = A[p][k], aqk = A[q][k];
                A[p][k] = c * apk - s * aqk;
                A[q][k] = s * apk + c * aqk;
            }
            for (int k = 0; k < 3; ++k) {
                double vkp = V[k][p], vkq = V[k][q];
                V[k][p] = c * vkp - s * vkq;
                V[k][q] = s * vkp + c * vkq;
            }
        }
    }
    double lam[3] = {A[0][0], A[1][1], A[2][2]};

    int idx[3] = {0, 1, 2};
    if (lam[idx[0]] < lam[idx[1]]) { int t = idx[0]; idx[0] = idx[1]; idx[1] = t; }
    if (lam[idx[1]] < lam[idx[2]]) { int t = idx[1]; idx[1] = idx[2]; idx[2] = t; }
    if (lam[idx[0]] < lam[idx[1]]) { int t = idx[0]; idx[0] = idx[1]; idx[1] = t; }

    double Vs[3][3], U[3][3];
    for (int k = 0; k < 3; ++k) {
        int c0 = idx[k];
        double l = lam[c0] > 1e-30 ? lam[c0] : 1e-30;
        double inv = 1.0 / sqrt(l);
        for (int i = 0; i < 3; ++i) Vs[i][k] = V[i][c0];
        for (int i = 0; i < 3; ++i) {
            double s = 0.0;
            for (int j = 0; j < 3; ++j) s += H[i][j] * Vs[j][k];
            U[i][k] = s * inv;
        }
    }

    double detH = H[0][0] * (H[1][1] * H[2][2] - H[1][2] * H[2][1])
                - H[0][1] * (H[1][0] * H[2][2] - H[1][2] * H[2][0])
                + H[0][2] * (H[1][0] * H[2][1] - H[1][1] * H[2][0]);
    double d = (detH < 0.0) ? -1.0 : 1.0;

    double R[3][3];
    for (int i = 0; i < 3; ++i)
        for (int j = 0; j < 3; ++j)
            R[i][j] = U[i][0] * Vs[j][0] + U[i][1] * Vs[j][1] + d * U[i][2] * Vs[j][2];

    double tv[3];
    for (int i = 0; i < 3; ++i)
        tv[i] = mu[i] - (R[i][0] * mg[0] + R[i][1] * mg[1] + R[i][2] * mg[2]);

    for (int i = 0; i < 3; ++i)
        for (int j = 0; j < 3; ++j) rt[i * 3 + j] = (float)R[i][j];
    for (int i = 0; i < 3; ++i) rt[9 + i] = (float)tv[i];
}

// ---------------- Pass 3: apply out = R * g + t (persistent blocks, LDS-staged, nt stores) ----------------
__global__ __launch_bounds__(BLK) void wra_apply(
    const float* __restrict__ g, const float* __restrict__ rt,
    float* __restrict__ out, int n4, int n, int ntiles)
{
    __shared__ f32x4 buf[768];

    float R00 = rt[0], R01 = rt[1], R02 = rt[2];
    float R10 = rt[3], R11 = rt[4], R12 = rt[5];
    float R20 = rt[6], R21 = rt[7], R22 = rt[8];
    float t0 = rt[9], t1 = rt[10], t2 = rt[11];

    const f32x4* __restrict__ g4 = (const f32x4*)g;
    f32x4* __restrict__ o4 = (f32x4*)out;

    const int tid = threadIdx.x;
    const int totc = 3 * n4;

    for (int t = blockIdx.x; t < ntiles; t += gridDim.x) {
        const int cb = t * 768;
#pragma unroll
        for (int k = 0; k < 3; ++k) {
            int c = cb + tid + 256 * k;
            if (c < totc) buf[tid + 256 * k] = g4[c];
        }
        __syncthreads();

        f32x4 ga = buf[3 * tid + 0], gb = buf[3 * tid + 1], gc = buf[3 * tid + 2];
        float qx0 = ga.x, qy0 = ga.y, qz0 = ga.z;
        float qx1 = ga.w, qy1 = gb.x, qz1 = gb.y;
        float qx2 = gb.z, qy2 = gb.w, qz2 = gc.x;
        float qx3 = gc.y, qy3 = gc.z, qz3 = gc.w;

        f32x4 r0, r1, r2;
        r0.x = R00*qx0 + R01*qy0 + R02*qz0 + t0;
        r0.y = R10*qx0 + R11*qy0 + R12*qz0 + t1;
        r0.z = R20*qx0 + R21*qy0 + R22*qz0 + t2;
        r0.w = R00*qx1 + R01*qy1 + R02*qz1 + t0;
        r1.x = R10*qx1 + R11*qy1 + R12*qz1 + t1;
        r1.y = R20*qx1 + R21*qy1 + R22*qz1 + t2;
        r1.z = R00*qx2 + R01*qy2 + R02*qz2 + t0;
        r1.w = R10*qx2 + R11*qy2 + R12*qz2 + t1;
        r2.x = R20*qx2 + R21*qy2 + R22*qz2 + t2;
        r2.y = R00*qx3 + R01*qy3 + R02*qz3 + t0;
        r2.z = R10*qx3 + R11*qy3 + R12*qz3 + t1;
        r2.w = R20*qx3 + R21*qy3 + R22*qz3 + t2;

        // write back to own slots (each thread touches only its own 3 chunks)
        buf[3 * tid + 0] = r0;
        buf[3 * tid + 1] = r1;
        buf[3 * tid + 2] = r2;
        __syncthreads();

#pragma unroll
        for (int k = 0; k < 3; ++k) {
            int c = cb + tid + 256 * k;
            if (c < totc) __builtin_nontemporal_store(buf[tid + 256 * k], &o4[c]);
        }
        __syncthreads();
    }

    // scalar tail
    int gtid = blockIdx.x * blockDim.x + threadIdx.x;
    int gstr = gridDim.x * blockDim.x;
    for (int r = n4 * 4 + gtid; r < n; r += gstr) {
        float Gx = g[3*r], Gy = g[3*r+1], Gz = g[3*r+2];
        out[3*r+0] = R00*Gx + R01*Gy + R02*Gz + t0;
        out[3*r+1] = R10*Gx + R11*Gy + R12*Gz + t1;
        out[3*r+2] = R20*Gx + R21*Gy + R22*Gz + t2;
    }
}

extern "C" void kernel_launch(void* const* d_in, const int* in_sizes, int n_in,
                              void* d_out, int out_size, void* d_ws, size_t ws_size,
                              hipStream_t stream)
{
    const float* x = (const float*)d_in[0];
    const float* g = (const float*)d_in[1];
    const float* w = (const float*)d_in[2];
    float* out = (float*)d_out;

    int n = in_sizes[2];      // number of points
    int n4 = n / 4;           // w float4-chunks
    int ntiles = (n4 + 255) / 256;
    if (ntiles < 1) ntiles = 1;

    int nbr = 2048;
    int maxnb = (int)((ws_size / sizeof(float) - 12) / 16);
    if (nbr > maxnb) nbr = maxnb;
    int need = (n4 + BLK - 1) / BLK;
    if (need < 1) need = 1;
    if (nbr > need) nbr = need;
    if (nbr < 1) nbr = 1;

    float* partials = (float*)d_ws;
    float* rt = partials + (size_t)nbr * 16;

    wra_reduce<<<nbr, BLK, 0, stream>>>(x, g, w, partials, n4, n);
    wra_solve<<<1, 64, 0, stream>>>(partials, nbr, rt);

    int nba = ntiles < 2048 ? ntiles : 2048;
    wra_apply<<<nba, BLK, 0, stream>>>(g, rt, out, n4, n, ntiles);
}

// Round 6
// 60.855 us; speedup vs baseline: 1.2949x; 1.0133x over previous
//
#include <hip/hip_runtime.h>
#include <math.h>

typedef float f32x4 __attribute__((ext_vector_type(4)));

#define BLK 256

__device__ __forceinline__ void accum4(
    float a[16], f32x4 xa, f32x4 xb, f32x4 xc,
    f32x4 ga, f32x4 gb, f32x4 gc, f32x4 wv)
{
    float px[4] = {xa.x, xa.w, xb.z, xc.y};
    float py[4] = {xa.y, xb.x, xb.w, xc.z};
    float pz[4] = {xa.z, xb.y, xc.x, xc.w};
    float qx[4] = {ga.x, ga.w, gb.z, gc.y};
    float qy[4] = {ga.y, gb.x, gb.w, gc.z};
    float qz[4] = {ga.z, gb.y, gc.x, gc.w};
    float wt[4] = {wv.x, wv.y, wv.z, wv.w};
#pragma unroll
    for (int k = 0; k < 4; ++k) {
        float wk = wt[k];
        float wpx = wk * px[k], wpy = wk * py[k], wpz = wk * pz[k];
        a[0] += wk;
        a[1] += wpx;         a[2] += wpy;         a[3] += wpz;
        a[4] += wk * qx[k];  a[5] += wk * qy[k];  a[6] += wk * qz[k];
        a[7]  += wpx * qx[k]; a[8]  += wpx * qy[k]; a[9]  += wpx * qz[k];
        a[10] += wpy * qx[k]; a[11] += wpy * qy[k]; a[12] += wpy * qz[k];
        a[13] += wpz * qx[k]; a[14] += wpz * qy[k]; a[15] += wpz * qz[k];
    }
}

// ---------------- Pass 1: raw moment reduction (direct regs, nt on x/w, 2x unroll) ----------------
// accumulators: a[0]=sum w; a[1..3]=sum w*x; a[4..6]=sum w*g; a[7..15]=sum w*x_i*g_j
// nt on x,w (never re-read); g plain so L3 keeps it warm for wra_apply.
__global__ __launch_bounds__(BLK) void wra_reduce(
    const float* __restrict__ x, const float* __restrict__ g,
    const float* __restrict__ w, float* __restrict__ partials,
    int n4, int n)
{
    float a[16];
#pragma unroll
    for (int i = 0; i < 16; ++i) a[i] = 0.f;

    const f32x4* __restrict__ x4 = (const f32x4*)x;
    const f32x4* __restrict__ g4 = (const f32x4*)g;
    const f32x4* __restrict__ w4 = (const f32x4*)w;

    int tid = blockIdx.x * blockDim.x + threadIdx.x;
    int stride = gridDim.x * blockDim.x;

    int i = tid;
    for (; i + stride < n4; i += 2 * stride) {
        int j = i + stride;
        f32x4 xa0 = __builtin_nontemporal_load(&x4[3*i+0]);
        f32x4 xb0 = __builtin_nontemporal_load(&x4[3*i+1]);
        f32x4 xc0 = __builtin_nontemporal_load(&x4[3*i+2]);
        f32x4 ga0 = g4[3*i+0];
        f32x4 gb0 = g4[3*i+1];
        f32x4 gc0 = g4[3*i+2];
        f32x4 wv0 = __builtin_nontemporal_load(&w4[i]);
        f32x4 xa1 = __builtin_nontemporal_load(&x4[3*j+0]);
        f32x4 xb1 = __builtin_nontemporal_load(&x4[3*j+1]);
        f32x4 xc1 = __builtin_nontemporal_load(&x4[3*j+2]);
        f32x4 ga1 = g4[3*j+0];
        f32x4 gb1 = g4[3*j+1];
        f32x4 gc1 = g4[3*j+2];
        f32x4 wv1 = __builtin_nontemporal_load(&w4[j]);
        accum4(a, xa0, xb0, xc0, ga0, gb0, gc0, wv0);
        accum4(a, xa1, xb1, xc1, ga1, gb1, gc1, wv1);
    }
    for (; i < n4; i += stride) {
        f32x4 xa = __builtin_nontemporal_load(&x4[3*i+0]);
        f32x4 xb = __builtin_nontemporal_load(&x4[3*i+1]);
        f32x4 xc = __builtin_nontemporal_load(&x4[3*i+2]);
        f32x4 ga = g4[3*i+0];
        f32x4 gb = g4[3*i+1];
        f32x4 gc = g4[3*i+2];
        f32x4 wv = __builtin_nontemporal_load(&w4[i]);
        accum4(a, xa, xb, xc, ga, gb, gc, wv);
    }

    // scalar tail (n not divisible by 4) — global thread 0
    if (blockIdx.x == 0 && threadIdx.x == 0) {
        for (int r = n4 * 4; r < n; ++r) {
            float wk = w[r];
            float X = x[3*r], Y = x[3*r+1], Z = x[3*r+2];
            float Gx = g[3*r], Gy = g[3*r+1], Gz = g[3*r+2];
            float wpx = wk * X, wpy = wk * Y, wpz = wk * Z;
            a[0] += wk;
            a[1] += wpx;      a[2] += wpy;      a[3] += wpz;
            a[4] += wk * Gx;  a[5] += wk * Gy;  a[6] += wk * Gz;
            a[7]  += wpx * Gx; a[8]  += wpx * Gy; a[9]  += wpx * Gz;
            a[10] += wpy * Gx; a[11] += wpy * Gy; a[12] += wpy * Gz;
            a[13] += wpz * Gx; a[14] += wpz * Gy; a[15] += wpz * Gz;
        }
    }

    // wave (64-lane) shuffle reduction per component
#pragma unroll
    for (int i2 = 0; i2 < 16; ++i2) {
        float v = a[i2];
        for (int off = 32; off > 0; off >>= 1) v += __shfl_down(v, off, 64);
        a[i2] = v;
    }
    __shared__ float red[4][16];
    int lane = threadIdx.x & 63;
    int wid  = threadIdx.x >> 6;
    if (lane == 0) {
#pragma unroll
        for (int i2 = 0; i2 < 16; ++i2) red[wid][i2] = a[i2];
    }
    __syncthreads();
    if (threadIdx.x < 16) {
        float s = red[0][threadIdx.x] + red[1][threadIdx.x]
                + red[2][threadIdx.x] + red[3][threadIdx.x];
        partials[blockIdx.x * 16 + threadIdx.x] = s;
    }
}

// ---------------- Pass 2: final reduce + 3x3 SVD solve (1 wave) ----------------
__global__ __launch_bounds__(64) void wra_solve(
    const float* __restrict__ partials, int nb, float* __restrict__ rt)
{
    int lane = threadIdx.x;
    double acc[16];
#pragma unroll
    for (int i = 0; i < 16; ++i) acc[i] = 0.0;
    for (int b = lane; b < nb; b += 64) {
#pragma unroll
        for (int i = 0; i < 16; ++i) acc[i] += (double)partials[b * 16 + i];
    }
#pragma unroll
    for (int i = 0; i < 16; ++i) {
        double v = acc[i];
        for (int off = 32; off > 0; off >>= 1) v += __shfl_down(v, off, 64);
        acc[i] = v;
    }
    if (lane != 0) return;

    double Sw = acc[0];
    double Sx[3] = {acc[1], acc[2], acc[3]};
    double Sg[3] = {acc[4], acc[5], acc[6]};
    double Hr[3][3];
    for (int i = 0; i < 3; ++i)
        for (int j = 0; j < 3; ++j) Hr[i][j] = acc[7 + i * 3 + j];

    double W = Sw + 1e-8;
    double mu[3], mg[3];
    for (int i = 0; i < 3; ++i) { mu[i] = Sx[i] / W; mg[i] = Sg[i] / W; }

    double H[3][3];
    for (int i = 0; i < 3; ++i)
        for (int j = 0; j < 3; ++j)
            H[i][j] = Hr[i][j] - mu[i] * Sg[j] - mg[j] * Sx[i] + mu[i] * mg[j] * Sw;

    double A[3][3];
    for (int i = 0; i < 3; ++i)
        for (int j = 0; j < 3; ++j) {
            double s = 0.0;
            for (int k = 0; k < 3; ++k) s += H[k][i] * H[k][j];
            A[i][j] = s;
        }

    // cyclic Jacobi (3x3 converges in <=6 sweeps; 10 for margin)
    double V[3][3] = {{1,0,0},{0,1,0},{0,0,1}};
    const int pr[3] = {0, 0, 1}, qr[3] = {1, 2, 2};
    for (int sweep = 0; sweep < 10; ++sweep) {
        for (int r = 0; r < 3; ++r) {
            int p = pr[r], q = qr[r];
            double apq = A[p][q];
            if (fabs(apq) < 1e-30) continue;
            double tau = (A[q][q] - A[p][p]) / (2.0 * apq);
            double t = (tau >= 0 ? 1.0 : -1.0) / (fabs(tau) + sqrt(1.0 + tau * tau));
            double c = 1.0 / sqrt(1.0 + t * t), s = t * c;
            for (int k = 0; k < 3; ++k) {
                double akp = A[k][p], akq = A[k][q];
                A[k][p] = c * akp - s * akq;
                A[k][q] = s * akp + c * akq;
            }
            for (int k = 0; k < 3; ++k) {
                double apk = A[p][k], aqk = A[q][k];
                A[p][k] = c * apk - s * aqk;
                A[q][k] = s * apk + c * aqk;
            }
            for (int k = 0; k < 3; ++k) {
                double vkp = V[k][p], vkq = V[k][q];
                V[k][p] = c * vkp - s * vkq;
                V[k][q] = s * vkp + c * vkq;
            }
        }
    }
    double lam[3] = {A[0][0], A[1][1], A[2][2]};

    int idx[3] = {0, 1, 2};
    if (lam[idx[0]] < lam[idx[1]]) { int t = idx[0]; idx[0] = idx[1]; idx[1] = t; }
    if (lam[idx[1]] < lam[idx[2]]) { int t = idx[1]; idx[1] = idx[2]; idx[2] = t; }
    if (lam[idx[0]] < lam[idx[1]]) { int t = idx[0]; idx[0] = idx[1]; idx[1] = t; }

    double Vs[3][3], U[3][3];
    for (int k = 0; k < 3; ++k) {
        int c0 = idx[k];
        double l = lam[c0] > 1e-30 ? lam[c0] : 1e-30;
        double inv = 1.0 / sqrt(l);
        for (int i = 0; i < 3; ++i) Vs[i][k] = V[i][c0];
        for (int i = 0; i < 3; ++i) {
            double s = 0.0;
            for (int j = 0; j < 3; ++j) s += H[i][j] * Vs[j][k];
            U[i][k] = s * inv;
        }
    }

    double detH = H[0][0] * (H[1][1] * H[2][2] - H[1][2] * H[2][1])
                - H[0][1] * (H[1][0] * H[2][2] - H[1][2] * H[2][0])
                + H[0][2] * (H[1][0] * H[2][1] - H[1][1] * H[2][0]);
    double d = (detH < 0.0) ? -1.0 : 1.0;

    double R[3][3];
    for (int i = 0; i < 3; ++i)
        for (int j = 0; j < 3; ++j)
            R[i][j] = U[i][0] * Vs[j][0] + U[i][1] * Vs[j][1] + d * U[i][2] * Vs[j][2];

    double tv[3];
    for (int i = 0; i < 3; ++i)
        tv[i] = mu[i] - (R[i][0] * mg[0] + R[i][1] * mg[1] + R[i][2] * mg[2]);

    for (int i = 0; i < 3; ++i)
        for (int j = 0; j < 3; ++j) rt[i * 3 + j] = (float)R[i][j];
    for (int i = 0; i < 3; ++i) rt[9 + i] = (float)tv[i];
}

// ---------------- Pass 3: apply out = R * g + t (persistent blocks, LDS-staged, plain stores) ----------------
__global__ __launch_bounds__(BLK) void wra_apply(
    const float* __restrict__ g, const float* __restrict__ rt,
    float* __restrict__ out, int n4, int n, int ntiles)
{
    __shared__ f32x4 buf[768];

    float R00 = rt[0], R01 = rt[1], R02 = rt[2];
    float R10 = rt[3], R11 = rt[4], R12 = rt[5];
    float R20 = rt[6], R21 = rt[7], R22 = rt[8];
    float t0 = rt[9], t1 = rt[10], t2 = rt[11];

    const f32x4* __restrict__ g4 = (const f32x4*)g;
    f32x4* __restrict__ o4 = (f32x4*)out;

    const int tid = threadIdx.x;
    const int totc = 3 * n4;

    for (int t = blockIdx.x; t < ntiles; t += gridDim.x) {
        const int cb = t * 768;
#pragma unroll
        for (int k = 0; k < 3; ++k) {
            int c = cb + tid + 256 * k;
            if (c < totc) buf[tid + 256 * k] = g4[c];
        }
        __syncthreads();

        f32x4 ga = buf[3 * tid + 0], gb = buf[3 * tid + 1], gc = buf[3 * tid + 2];
        float qx0 = ga.x, qy0 = ga.y, qz0 = ga.z;
        float qx1 = ga.w, qy1 = gb.x, qz1 = gb.y;
        float qx2 = gb.z, qy2 = gb.w, qz2 = gc.x;
        float qx3 = gc.y, qy3 = gc.z, qz3 = gc.w;

        f32x4 r0, r1, r2;
        r0.x = R00*qx0 + R01*qy0 + R02*qz0 + t0;
        r0.y = R10*qx0 + R11*qy0 + R12*qz0 + t1;
        r0.z = R20*qx0 + R21*qy0 + R22*qz0 + t2;
        r0.w = R00*qx1 + R01*qy1 + R02*qz1 + t0;
        r1.x = R10*qx1 + R11*qy1 + R12*qz1 + t1;
        r1.y = R20*qx1 + R21*qy1 + R22*qz1 + t2;
        r1.z = R00*qx2 + R01*qy2 + R02*qz2 + t0;
        r1.w = R10*qx2 + R11*qy2 + R12*qz2 + t1;
        r2.x = R20*qx2 + R21*qy2 + R22*qz2 + t2;
        r2.y = R00*qx3 + R01*qy3 + R02*qz3 + t0;
        r2.z = R10*qx3 + R11*qy3 + R12*qz3 + t1;
        r2.w = R20*qx3 + R21*qy3 + R22*qz3 + t2;

        buf[3 * tid + 0] = r0;
        buf[3 * tid + 1] = r1;
        buf[3 * tid + 2] = r2;
        __syncthreads();

#pragma unroll
        for (int k = 0; k < 3; ++k) {
            int c = cb + tid + 256 * k;
            if (c < totc) o4[c] = buf[tid + 256 * k];
        }
        __syncthreads();
    }

    // scalar tail
    int gtid = blockIdx.x * blockDim.x + threadIdx.x;
    int gstr = gridDim.x * blockDim.x;
    for (int r = n4 * 4 + gtid; r < n; r += gstr) {
        float Gx = g[3*r], Gy = g[3*r+1], Gz = g[3*r+2];
        out[3*r+0] = R00*Gx + R01*Gy + R02*Gz + t0;
        out[3*r+1] = R10*Gx + R11*Gy + R12*Gz + t1;
        out[3*r+2] = R20*Gx + R21*Gy + R22*Gz + t2;
    }
}

extern "C" void kernel_launch(void* const* d_in, const int* in_sizes, int n_in,
                              void* d_out, int out_size, void* d_ws, size_t ws_size,
                              hipStream_t stream)
{
    const float* x = (const float*)d_in[0];
    const float* g = (const float*)d_in[1];
    const float* w = (const float*)d_in[2];
    float* out = (float*)d_out;

    int n = in_sizes[2];      // number of points
    int n4 = n / 4;           // w float4-chunks
    int ntiles = (n4 + 255) / 256;
    if (ntiles < 1) ntiles = 1;

    int nbr = 2048;
    int maxnb = (int)((ws_size / sizeof(float) - 12) / 16);
    if (nbr > maxnb) nbr = maxnb;
    int need = (n4 + BLK - 1) / BLK;
    if (need < 1) need = 1;
    if (nbr > need) nbr = need;
    if (nbr < 1) nbr = 1;

    float* partials = (float*)d_ws;
    float* rt = partials + (size_t)nbr * 16;

    wra_reduce<<<nbr, BLK, 0, stream>>>(x, g, w, partials, n4, n);
    wra_solve<<<1, 64, 0, stream>>>(partials, nbr, rt);

    int nba = ntiles < 2048 ? ntiles : 2048;
    wra_apply<<<nba, BLK, 0, stream>>>(g, rt, out, n4, n, ntiles);
}

// Round 8
// 59.770 us; speedup vs baseline: 1.3184x; 1.0181x over previous
//
#include <hip/hip_runtime.h>
#include <math.h>

typedef float    f32x4 __attribute__((ext_vector_type(4)));
typedef _Float16 f16x4 __attribute__((ext_vector_type(4)));

#define BLK 256

__device__ __forceinline__ void accum4(
    float a[16], f32x4 xa, f32x4 xb, f32x4 xc,
    f32x4 ga, f32x4 gb, f32x4 gc, f32x4 wv)
{
    float px[4] = {xa.x, xa.w, xb.z, xc.y};
    float py[4] = {xa.y, xb.x, xb.w, xc.z};
    float pz[4] = {xa.z, xb.y, xc.x, xc.w};
    float qx[4] = {ga.x, ga.w, gb.z, gc.y};
    float qy[4] = {ga.y, gb.x, gb.w, gc.z};
    float qz[4] = {ga.z, gb.y, gc.x, gc.w};
    float wt[4] = {wv.x, wv.y, wv.z, wv.w};
#pragma unroll
    for (int k = 0; k < 4; ++k) {
        float wk = wt[k];
        float wpx = wk * px[k], wpy = wk * py[k], wpz = wk * pz[k];
        a[0] += wk;
        a[1] += wpx;         a[2] += wpy;         a[3] += wpz;
        a[4] += wk * qx[k];  a[5] += wk * qy[k];  a[6] += wk * qz[k];
        a[7]  += wpx * qx[k]; a[8]  += wpx * qy[k]; a[9]  += wpx * qz[k];
        a[10] += wpy * qx[k]; a[11] += wpy * qy[k]; a[12] += wpy * qz[k];
        a[13] += wpz * qx[k]; a[14] += wpz * qy[k]; a[15] += wpz * qz[k];
    }
}

// ---------------- Pass 1: raw moments + emit f16 copy of g ----------------
// a[0]=sum w; a[1..3]=sum w*x; a[4..6]=sum w*g; a[7..15]=sum w*x_i*g_j
// nt loads on x,w (never re-read); g plain (L3 keeps it for tail); g16 plain
// stores (re-read by wra_apply_h — must stay cached).
__global__ __launch_bounds__(BLK) void wra_reduce(
    const float* __restrict__ x, const float* __restrict__ g,
    const float* __restrict__ w, float* __restrict__ partials,
    f16x4* __restrict__ g16, int n4, int n)
{
    float a[16];
#pragma unroll
    for (int i = 0; i < 16; ++i) a[i] = 0.f;

    const f32x4* __restrict__ x4 = (const f32x4*)x;
    const f32x4* __restrict__ g4 = (const f32x4*)g;
    const f32x4* __restrict__ w4 = (const f32x4*)w;

    int tid = blockIdx.x * blockDim.x + threadIdx.x;
    int stride = gridDim.x * blockDim.x;

    int i = tid;
    for (; i + stride < n4; i += 2 * stride) {
        int j = i + stride;
        f32x4 xa0 = __builtin_nontemporal_load(&x4[3*i+0]);
        f32x4 xb0 = __builtin_nontemporal_load(&x4[3*i+1]);
        f32x4 xc0 = __builtin_nontemporal_load(&x4[3*i+2]);
        f32x4 ga0 = g4[3*i+0];
        f32x4 gb0 = g4[3*i+1];
        f32x4 gc0 = g4[3*i+2];
        f32x4 wv0 = __builtin_nontemporal_load(&w4[i]);
        f32x4 xa1 = __builtin_nontemporal_load(&x4[3*j+0]);
        f32x4 xb1 = __builtin_nontemporal_load(&x4[3*j+1]);
        f32x4 xc1 = __builtin_nontemporal_load(&x4[3*j+2]);
        f32x4 ga1 = g4[3*j+0];
        f32x4 gb1 = g4[3*j+1];
        f32x4 gc1 = g4[3*j+2];
        f32x4 wv1 = __builtin_nontemporal_load(&w4[j]);
        if (g16) {
            g16[3*i+0] = __builtin_convertvector(ga0, f16x4);
            g16[3*i+1] = __builtin_convertvector(gb0, f16x4);
            g16[3*i+2] = __builtin_convertvector(gc0, f16x4);
            g16[3*j+0] = __builtin_convertvector(ga1, f16x4);
            g16[3*j+1] = __builtin_convertvector(gb1, f16x4);
            g16[3*j+2] = __builtin_convertvector(gc1, f16x4);
        }
        accum4(a, xa0, xb0, xc0, ga0, gb0, gc0, wv0);
        accum4(a, xa1, xb1, xc1, ga1, gb1, gc1, wv1);
    }
    for (; i < n4; i += stride) {
        f32x4 xa = __builtin_nontemporal_load(&x4[3*i+0]);
        f32x4 xb = __builtin_nontemporal_load(&x4[3*i+1]);
        f32x4 xc = __builtin_nontemporal_load(&x4[3*i+2]);
        f32x4 ga = g4[3*i+0];
        f32x4 gb = g4[3*i+1];
        f32x4 gc = g4[3*i+2];
        f32x4 wv = __builtin_nontemporal_load(&w4[i]);
        if (g16) {
            g16[3*i+0] = __builtin_convertvector(ga, f16x4);
            g16[3*i+1] = __builtin_convertvector(gb, f16x4);
            g16[3*i+2] = __builtin_convertvector(gc, f16x4);
        }
        accum4(a, xa, xb, xc, ga, gb, gc, wv);
    }

    // scalar tail (n not divisible by 4) — global thread 0
    if (blockIdx.x == 0 && threadIdx.x == 0) {
        for (int r = n4 * 4; r < n; ++r) {
            float wk = w[r];
            float X = x[3*r], Y = x[3*r+1], Z = x[3*r+2];
            float Gx = g[3*r], Gy = g[3*r+1], Gz = g[3*r+2];
            float wpx = wk * X, wpy = wk * Y, wpz = wk * Z;
            a[0] += wk;
            a[1] += wpx;      a[2] += wpy;      a[3] += wpz;
            a[4] += wk * Gx;  a[5] += wk * Gy;  a[6] += wk * Gz;
            a[7]  += wpx * Gx; a[8]  += wpx * Gy; a[9]  += wpx * Gz;
            a[10] += wpy * Gx; a[11] += wpy * Gy; a[12] += wpy * Gz;
            a[13] += wpz * Gx; a[14] += wpz * Gy; a[15] += wpz * Gz;
        }
    }

    // wave (64-lane) shuffle reduction per component
#pragma unroll
    for (int i2 = 0; i2 < 16; ++i2) {
        float v = a[i2];
        for (int off = 32; off > 0; off >>= 1) v += __shfl_down(v, off, 64);
        a[i2] = v;
    }
    __shared__ float red[4][16];
    int lane = threadIdx.x & 63;
    int wid  = threadIdx.x >> 6;
    if (lane == 0) {
#pragma unroll
        for (int i2 = 0; i2 < 16; ++i2) red[wid][i2] = a[i2];
    }
    __syncthreads();
    if (threadIdx.x < 16) {
        float s = red[0][threadIdx.x] + red[1][threadIdx.x]
                + red[2][threadIdx.x] + red[3][threadIdx.x];
        partials[blockIdx.x * 16 + threadIdx.x] = s;
    }
}

// ---------------- Pass 2: final reduce + 3x3 SVD solve (1 wave) ----------------
__global__ __launch_bounds__(64) void wra_solve(
    const float* __restrict__ partials, int nb, float* __restrict__ rt)
{
    int lane = threadIdx.x;
    double acc[16];
#pragma unroll
    for (int i = 0; i < 16; ++i) acc[i] = 0.0;
    for (int b = lane; b < nb; b += 64) {
#pragma unroll
        for (int i = 0; i < 16; ++i) acc[i] += (double)partials[b * 16 + i];
    }
#pragma unroll
    for (int i = 0; i < 16; ++i) {
        double v = acc[i];
        for (int off = 32; off > 0; off >>= 1) v += __shfl_down(v, off, 64);
        acc[i] = v;
    }
    if (lane != 0) return;

    double Sw = acc[0];
    double Sx[3] = {acc[1], acc[2], acc[3]};
    double Sg[3] = {acc[4], acc[5], acc[6]};
    double Hr[3][3];
    for (int i = 0; i < 3; ++i)
        for (int j = 0; j < 3; ++j) Hr[i][j] = acc[7 + i * 3 + j];

    double W = Sw + 1e-8;
    double mu[3], mg[3];
    for (int i = 0; i < 3; ++i) { mu[i] = Sx[i] / W; mg[i] = Sg[i] / W; }

    double H[3][3];
    for (int i = 0; i < 3; ++i)
        for (int j = 0; j < 3; ++j)
            H[i][j] = Hr[i][j] - mu[i] * Sg[j] - mg[j] * Sx[i] + mu[i] * mg[j] * Sw;

    double A[3][3];
    for (int i = 0; i < 3; ++i)
        for (int j = 0; j < 3; ++j) {
            double s = 0.0;
            for (int k = 0; k < 3; ++k) s += H[k][i] * H[k][j];
            A[i][j] = s;
        }

    // cyclic Jacobi (3x3 converges in <=6 sweeps; 10 for margin)
    double V[3][3] = {{1,0,0},{0,1,0},{0,0,1}};
    const int pr[3] = {0, 0, 1}, qr[3] = {1, 2, 2};
    for (int sweep = 0; sweep < 10; ++sweep) {
        for (int r = 0; r < 3; ++r) {
            int p = pr[r], q = qr[r];
            double apq = A[p][q];
            if (fabs(apq) < 1e-30) continue;
            double tau = (A[q][q] - A[p][p]) / (2.0 * apq);
            double t = (tau >= 0 ? 1.0 : -1.0) / (fabs(tau) + sqrt(1.0 + tau * tau));
            double c = 1.0 / sqrt(1.0 + t * t), s = t * c;
            for (int k = 0; k < 3; ++k) {
                double akp = A[k][p], akq = A[k][q];
                A[k][p] = c * akp - s * akq;
                A[k][q] = s * akp + c * akq;
            }
            for (int k = 0; k < 3; ++k) {
                double apk = A[p][k], aqk = A[q][k];
                A[p][k] = c * apk - s * aqk;
                A[q][k] = s * apk + c * aqk;
            }
            for (int k = 0; k < 3; ++k) {
                double vkp = V[k][p], vkq = V[k][q];
                V[k][p] = c * vkp - s * vkq;
                V[k][q] = s * vkp + c * vkq;
            }
        }
    }
    double lam[3] = {A[0][0], A[1][1], A[2][2]};

    int idx[3] = {0, 1, 2};
    if (lam[idx[0]] < lam[idx[1]]) { int t = idx[0]; idx[0] = idx[1]; idx[1] = t; }
    if (lam[idx[1]] < lam[idx[2]]) { int t = idx[1]; idx[1] = idx[2]; idx[2] = t; }
    if (lam[idx[0]] < lam[idx[1]]) { int t = idx[0]; idx[0] = idx[1]; idx[1] = t; }

    double Vs[3][3], U[3][3];
    for (int k = 0; k < 3; ++k) {
        int c0 = idx[k];
        double l = lam[c0] > 1e-30 ? lam[c0] : 1e-30;
        double inv = 1.0 / sqrt(l);
        for (int i = 0; i < 3; ++i) Vs[i][k] = V[i][c0];
        for (int i = 0; i < 3; ++i) {
            double s = 0.0;
            for (int j = 0; j < 3; ++j) s += H[i][j] * Vs[j][k];
            U[i][k] = s * inv;
        }
    }

    double detH = H[0][0] * (H[1][1] * H[2][2] - H[1][2] * H[2][1])
                - H[0][1] * (H[1][0] * H[2][2] - H[1][2] * H[2][0])
                + H[0][2] * (H[1][0] * H[2][1] - H[1][1] * H[2][0]);
    double d = (detH < 0.0) ? -1.0 : 1.0;

    double R[3][3];
    for (int i = 0; i < 3; ++i)
        for (int j = 0; j < 3; ++j)
            R[i][j] = U[i][0] * Vs[j][0] + U[i][1] * Vs[j][1] + d * U[i][2] * Vs[j][2];

    double tv[3];
    for (int i = 0; i < 3; ++i)
        tv[i] = mu[i] - (R[i][0] * mg[0] + R[i][1] * mg[1] + R[i][2] * mg[2]);

    for (int i = 0; i < 3; ++i)
        for (int j = 0; j < 3; ++j) rt[i * 3 + j] = (float)R[i][j];
    for (int i = 0; i < 3; ++i) rt[9 + i] = (float)tv[i];
}

// ---------------- Pass 3a: apply from f16 copy (half the read bytes) ----------------
__global__ __launch_bounds__(BLK) void wra_apply_h(
    const f16x4* __restrict__ g16, const float* __restrict__ g,
    const float* __restrict__ rt, float* __restrict__ out,
    int n4, int n, int ntiles)
{
    __shared__ f16x4 ibuf[768];   // 6 KB
    __shared__ f32x4 obuf[768];   // 12 KB

    float R00 = rt[0], R01 = rt[1], R02 = rt[2];
    float R10 = rt[3], R11 = rt[4], R12 = rt[5];
    float R20 = rt[6], R21 = rt[7], R22 = rt[8];
    float t0 = rt[9], t1 = rt[10], t2 = rt[11];

    f32x4* __restrict__ o4 = (f32x4*)out;

    const int tid = threadIdx.x;
    const int totc = 3 * n4;

    for (int t = blockIdx.x; t < ntiles; t += gridDim.x) {
        const int cb = t * 768;
#pragma unroll
        for (int k = 0; k < 3; ++k) {
            int c = cb + tid + 256 * k;
            if (c < totc) ibuf[tid + 256 * k] = g16[c];
        }
        __syncthreads();

        f32x4 ga = __builtin_convertvector(ibuf[3 * tid + 0], f32x4);
        f32x4 gb = __builtin_convertvector(ibuf[3 * tid + 1], f32x4);
        f32x4 gc = __builtin_convertvector(ibuf[3 * tid + 2], f32x4);
        float qx0 = ga.x, qy0 = ga.y, qz0 = ga.z;
        float qx1 = ga.w, qy1 = gb.x, qz1 = gb.y;
        float qx2 = gb.z, qy2 = gb.w, qz2 = gc.x;
        float qx3 = gc.y, qy3 = gc.z, qz3 = gc.w;

        f32x4 r0, r1, r2;
        r0.x = R00*qx0 + R01*qy0 + R02*qz0 + t0;
        r0.y = R10*qx0 + R11*qy0 + R12*qz0 + t1;
        r0.z = R20*qx0 + R21*qy0 + R22*qz0 + t2;
        r0.w = R00*qx1 + R01*qy1 + R02*qz1 + t0;
        r1.x = R10*qx1 + R11*qy1 + R12*qz1 + t1;
        r1.y = R20*qx1 + R21*qy1 + R22*qz1 + t2;
        r1.z = R00*qx2 + R01*qy2 + R02*qz2 + t0;
        r1.w = R10*qx2 + R11*qy2 + R12*qz2 + t1;
        r2.x = R20*qx2 + R21*qy2 + R22*qz2 + t2;
        r2.y = R00*qx3 + R01*qy3 + R02*qz3 + t0;
        r2.z = R10*qx3 + R11*qy3 + R12*qz3 + t1;
        r2.w = R20*qx3 + R21*qy3 + R22*qz3 + t2;

        obuf[3 * tid + 0] = r0;
        obuf[3 * tid + 1] = r1;
        obuf[3 * tid + 2] = r2;
        __syncthreads();

#pragma unroll
        for (int k = 0; k < 3; ++k) {
            int c = cb + tid + 256 * k;
            if (c < totc) o4[c] = obuf[tid + 256 * k];
        }
        __syncthreads();
    }

    // scalar tail (full f32 from original g)
    int gtid = blockIdx.x * blockDim.x + threadIdx.x;
    int gstr = gridDim.x * blockDim.x;
    for (int r = n4 * 4 + gtid; r < n; r += gstr) {
        float Gx = g[3*r], Gy = g[3*r+1], Gz = g[3*r+2];
        out[3*r+0] = R00*Gx + R01*Gy + R02*Gz + t0;
        out[3*r+1] = R10*Gx + R11*Gy + R12*Gz + t1;
        out[3*r+2] = R20*Gx + R21*Gy + R22*Gz + t2;
    }
}

// ---------------- Pass 3b: fallback apply from f32 g (R2-proven) ----------------
__global__ __launch_bounds__(BLK) void wra_apply_f(
    const float* __restrict__ g, const float* __restrict__ rt,
    float* __restrict__ out, int n4, int n, int ntiles)
{
    __shared__ f32x4 buf[768];

    float R00 = rt[0], R01 = rt[1], R02 = rt[2];
    float R10 = rt[3], R11 = rt[4], R12 = rt[5];
    float R20 = rt[6], R21 = rt[7], R22 = rt[8];
    float t0 = rt[9], t1 = rt[10], t2 = rt[11];

    const f32x4* __restrict__ g4 = (const f32x4*)g;
    f32x4* __restrict__ o4 = (f32x4*)out;

    const int tid = threadIdx.x;
    const int totc = 3 * n4;

    for (int t = blockIdx.x; t < ntiles; t += gridDim.x) {
        const int cb = t * 768;
#pragma unroll
        for (int k = 0; k < 3; ++k) {
            int c = cb + tid + 256 * k;
            if (c < totc) buf[tid + 256 * k] = g4[c];
        }
        __syncthreads();

        f32x4 ga = buf[3 * tid + 0], gb = buf[3 * tid + 1], gc = buf[3 * tid + 2];
        float qx0 = ga.x, qy0 = ga.y, qz0 = ga.z;
        float qx1 = ga.w, qy1 = gb.x, qz1 = gb.y;
        float qx2 = gb.z, qy2 = gb.w, qz2 = gc.x;
        float qx3 = gc.y, qy3 = gc.z, qz3 = gc.w;

        f32x4 r0, r1, r2;
        r0.x = R00*qx0 + R01*qy0 + R02*qz0 + t0;
        r0.y = R10*qx0 + R11*qy0 + R12*qz0 + t1;
        r0.z = R20*qx0 + R21*qy0 + R22*qz0 + t2;
        r0.w = R00*qx1 + R01*qy1 + R02*qz1 + t0;
        r1.x = R10*qx1 + R11*qy1 + R12*qz1 + t1;
        r1.y = R20*qx1 + R21*qy1 + R22*qz1 + t2;
        r1.z = R00*qx2 + R01*qy2 + R02*qz2 + t0;
        r1.w = R10*qx2 + R11*qy2 + R12*qz2 + t1;
        r2.x = R20*qx2 + R21*qy2 + R22*qz2 + t2;
        r2.y = R00*qx3 + R01*qy3 + R02*qz3 + t0;
        r2.z = R10*qx3 + R11*qy3 + R12*qz3 + t1;
        r2.w = R20*qx3 + R21*qy3 + R22*qz3 + t2;

        buf[3 * tid + 0] = r0;
        buf[3 * tid + 1] = r1;
        buf[3 * tid + 2] = r2;
        __syncthreads();

#pragma unroll
        for (int k = 0; k < 3; ++k) {
            int c = cb + tid + 256 * k;
            if (c < totc) o4[c] = buf[tid + 256 * k];
        }
        __syncthreads();
    }

    int gtid = blockIdx.x * blockDim.x + threadIdx.x;
    int gstr = gridDim.x * blockDim.x;
    for (int r = n4 * 4 + gtid; r < n; r += gstr) {
        float Gx = g[3*r], Gy = g[3*r+1], Gz = g[3*r+2];
        out[3*r+0] = R00*Gx + R01*Gy + R02*Gz + t0;
        out[3*r+1] = R10*Gx + R11*Gy + R12*Gz + t1;
        out[3*r+2] = R20*Gx + R21*Gy + R22*Gz + t2;
    }
}

extern "C" void kernel_launch(void* const* d_in, const int* in_sizes, int n_in,
                              void* d_out, int out_size, void* d_ws, size_t ws_size,
                              hipStream_t stream)
{
    const float* x = (const float*)d_in[0];
    const float* g = (const float*)d_in[1];
    const float* w = (const float*)d_in[2];
    float* out = (float*)d_out;

    int n = in_sizes[2];      // number of points
    int n4 = n / 4;           // float4 groups
    int ntiles = (n4 + 255) / 256;
    if (ntiles < 1) ntiles = 1;

    int nbr = 2048;
    int need = (n4 + BLK - 1) / BLK;
    if (need < 1) need = 1;
    if (nbr > need) nbr = need;
    // partials must fit even without g16
    int maxnb = (int)((ws_size / sizeof(float) - 12) / 16);
    if (nbr > maxnb) nbr = maxnb;
    if (nbr < 1) nbr = 1;

    float* partials = (float*)d_ws;
    float* rt = partials + (size_t)nbr * 16;

    // f16 g copy in ws (24 MB at n=4M), 256-byte aligned
    size_t base = ((size_t)nbr * 16 + 12) * sizeof(float);
    size_t g16off = (base + 255) & ~(size_t)255;
    size_t g16bytes = (size_t)3 * (size_t)n4 * sizeof(f16x4);
    bool use16 = (n4 > 0) && (ws_size >= g16off + g16bytes);
    f16x4* g16 = use16 ? (f16x4*)((char*)d_ws + g16off) : (f16x4*)nullptr;

    wra_reduce<<<nbr, BLK, 0, stream>>>(x, g, w, partials, g16, n4, n);
    wra_solve<<<1, 64, 0, stream>>>(partials, nbr, rt);

    int nba = ntiles < 2048 ? ntiles : 2048;
    if (use16)
        wra_apply_h<<<nba, BLK, 0, stream>>>(g16, g, rt, out, n4, n, ntiles);
    else
        wra_apply_f<<<nba, BLK, 0, stream>>>(g, rt, out, n4, n, ntiles);
}

// Round 9
// 53.417 us; speedup vs baseline: 1.4752x; 1.1189x over previous
//
#include <hip/hip_runtime.h>
#include <math.h>

typedef float    f32x4 __attribute__((ext_vector_type(4)));
typedef _Float16 f16x4 __attribute__((ext_vector_type(4)));

#define BLK 256
// tile = 256 w-chunks = 1024 points = 768 x/g float4-chunks

// ---------------- Pass 1: R2-style LDS-staged reduce + f16 g-copy ----------------
// accumulators: a[0]=sum w; a[1..3]=sum w*x; a[4..6]=sum w*g; a[7..15]=sum w*x_i*g_j
__global__ __launch_bounds__(BLK) void wra_reduce(
    const float* __restrict__ x, const float* __restrict__ g,
    const float* __restrict__ w, float* __restrict__ partials,
    f16x4* __restrict__ g16, int n4, int n, int ntiles)
{
    __shared__ f32x4 xs[768];
    __shared__ f32x4 gs[768];

    float a[16];
#pragma unroll
    for (int i = 0; i < 16; ++i) a[i] = 0.f;

    const f32x4* __restrict__ x4 = (const f32x4*)x;
    const f32x4* __restrict__ g4 = (const f32x4*)g;
    const f32x4* __restrict__ w4 = (const f32x4*)w;

    const int tid = threadIdx.x;
    const int totc = 3 * n4;
    const f32x4 z4 = {0.f, 0.f, 0.f, 0.f};

    for (int t = blockIdx.x; t < ntiles; t += gridDim.x) {
        const int cb = t * 768;
        // stage: lane-contiguous float4 loads; emit f16 copy of g (lane-contiguous 8B stores)
#pragma unroll
        for (int k = 0; k < 3; ++k) {
            int c = cb + tid + 256 * k;
            f32x4 xv = z4, gv = z4;
            if (c < totc) { xv = x4[c]; gv = g4[c]; }
            xs[tid + 256 * k] = xv;
            gs[tid + 256 * k] = gv;
            if (g16 && c < totc) g16[c] = __builtin_convertvector(gv, f16x4);
        }
        int wc = t * 256 + tid;
        f32x4 wv = (wc < n4) ? w4[wc] : z4;
        __syncthreads();

        f32x4 xa = xs[3 * tid + 0], xb = xs[3 * tid + 1], xc = xs[3 * tid + 2];
        f32x4 ga = gs[3 * tid + 0], gb = gs[3 * tid + 1], gc = gs[3 * tid + 2];

        float px[4] = {xa.x, xa.w, xb.z, xc.y};
        float py[4] = {xa.y, xb.x, xb.w, xc.z};
        float pz[4] = {xa.z, xb.y, xc.x, xc.w};
        float qx[4] = {ga.x, ga.w, gb.z, gc.y};
        float qy[4] = {ga.y, gb.x, gb.w, gc.z};
        float qz[4] = {ga.z, gb.y, gc.x, gc.w};
        float wt[4] = {wv.x, wv.y, wv.z, wv.w};
#pragma unroll
        for (int k = 0; k < 4; ++k) {
            float wk = wt[k];
            float wpx = wk * px[k], wpy = wk * py[k], wpz = wk * pz[k];
            a[0] += wk;
            a[1] += wpx;         a[2] += wpy;         a[3] += wpz;
            a[4] += wk * qx[k];  a[5] += wk * qy[k];  a[6] += wk * qz[k];
            a[7]  += wpx * qx[k]; a[8]  += wpx * qy[k]; a[9]  += wpx * qz[k];
            a[10] += wpy * qx[k]; a[11] += wpy * qy[k]; a[12] += wpy * qz[k];
            a[13] += wpz * qx[k]; a[14] += wpz * qy[k]; a[15] += wpz * qz[k];
        }
        __syncthreads();
    }

    // scalar tail (n not divisible by 4) — block 0 / thread 0
    if (blockIdx.x == 0 && tid == 0) {
        for (int r = n4 * 4; r < n; ++r) {
            float wk = w[r];
            float X = x[3*r], Y = x[3*r+1], Z = x[3*r+2];
            float Gx = g[3*r], Gy = g[3*r+1], Gz = g[3*r+2];
            float wpx = wk * X, wpy = wk * Y, wpz = wk * Z;
            a[0] += wk;
            a[1] += wpx;      a[2] += wpy;      a[3] += wpz;
            a[4] += wk * Gx;  a[5] += wk * Gy;  a[6] += wk * Gz;
            a[7]  += wpx * Gx; a[8]  += wpx * Gy; a[9]  += wpx * Gz;
            a[10] += wpy * Gx; a[11] += wpy * Gy; a[12] += wpy * Gz;
            a[13] += wpz * Gx; a[14] += wpz * Gy; a[15] += wpz * Gz;
        }
    }

    // wave (64-lane) shuffle reduction per component
#pragma unroll
    for (int i = 0; i < 16; ++i) {
        float v = a[i];
        for (int off = 32; off > 0; off >>= 1) v += __shfl_down(v, off, 64);
        a[i] = v;
    }
    __shared__ float red[4][16];
    int lane = tid & 63;
    int wid  = tid >> 6;
    if (lane == 0) {
#pragma unroll
        for (int i = 0; i < 16; ++i) red[wid][i] = a[i];
    }
    __syncthreads();
    if (tid < 16) {
        float s = red[0][tid] + red[1][tid] + red[2][tid] + red[3][tid];
        partials[blockIdx.x * 16 + tid] = s;
    }
}

// ---------------- Pass 2: final reduce + 3x3 SVD solve (1 wave) ----------------
__global__ __launch_bounds__(64) void wra_solve(
    const float* __restrict__ partials, int nb, float* __restrict__ rt)
{
    int lane = threadIdx.x;
    double acc[16];
#pragma unroll
    for (int i = 0; i < 16; ++i) acc[i] = 0.0;
    for (int b = lane; b < nb; b += 64) {
#pragma unroll
        for (int i = 0; i < 16; ++i) acc[i] += (double)partials[b * 16 + i];
    }
#pragma unroll
    for (int i = 0; i < 16; ++i) {
        double v = acc[i];
        for (int off = 32; off > 0; off >>= 1) v += __shfl_down(v, off, 64);
        acc[i] = v;
    }
    if (lane != 0) return;

    double Sw = acc[0];
    double Sx[3] = {acc[1], acc[2], acc[3]};
    double Sg[3] = {acc[4], acc[5], acc[6]};
    double Hr[3][3];
    for (int i = 0; i < 3; ++i)
        for (int j = 0; j < 3; ++j) Hr[i][j] = acc[7 + i * 3 + j];

    double W = Sw + 1e-8;
    double mu[3], mg[3];
    for (int i = 0; i < 3; ++i) { mu[i] = Sx[i] / W; mg[i] = Sg[i] / W; }

    double H[3][3];
    for (int i = 0; i < 3; ++i)
        for (int j = 0; j < 3; ++j)
            H[i][j] = Hr[i][j] - mu[i] * Sg[j] - mg[j] * Sx[i] + mu[i] * mg[j] * Sw;

    double A[3][3];
    for (int i = 0; i < 3; ++i)
        for (int j = 0; j < 3; ++j) {
            double s = 0.0;
            for (int k = 0; k < 3; ++k) s += H[k][i] * H[k][j];
            A[i][j] = s;
        }

    double V[3][3] = {{1,0,0},{0,1,0},{0,0,1}};
    const int pr[3] = {0, 0, 1}, qr[3] = {1, 2, 2};
    for (int sweep = 0; sweep < 10; ++sweep) {
        for (int r = 0; r < 3; ++r) {
            int p = pr[r], q = qr[r];
            double apq = A[p][q];
            if (fabs(apq) < 1e-30) continue;
            double tau = (A[q][q] - A[p][p]) / (2.0 * apq);
            double t = (tau >= 0 ? 1.0 : -1.0) / (fabs(tau) + sqrt(1.0 + tau * tau));
            double c = 1.0 / sqrt(1.0 + t * t), s = t * c;
            for (int k = 0; k < 3; ++k) {
                double akp = A[k][p], akq = A[k][q];
                A[k][p] = c * akp - s * akq;
                A[k][q] = s * akp + c * akq;
            }
            for (int k = 0; k < 3; ++k) {
                double apk = A[p][k], aqk = A[q][k];
                A[p][k] = c * apk - s * aqk;
                A[q][k] = s * apk + c * aqk;
            }
            for (int k = 0; k < 3; ++k) {
                double vkp = V[k][p], vkq = V[k][q];
                V[k][p] = c * vkp - s * vkq;
                V[k][q] = s * vkp + c * vkq;
            }
        }
    }
    double lam[3] = {A[0][0], A[1][1], A[2][2]};

    int idx[3] = {0, 1, 2};
    if (lam[idx[0]] < lam[idx[1]]) { int t = idx[0]; idx[0] = idx[1]; idx[1] = t; }
    if (lam[idx[1]] < lam[idx[2]]) { int t = idx[1]; idx[1] = idx[2]; idx[2] = t; }
    if (lam[idx[0]] < lam[idx[1]]) { int t = idx[0]; idx[0] = idx[1]; idx[1] = t; }

    double Vs[3][3], U[3][3];
    for (int k = 0; k < 3; ++k) {
        int c0 = idx[k];
        double l = lam[c0] > 1e-30 ? lam[c0] : 1e-30;
        double inv = 1.0 / sqrt(l);
        for (int i = 0; i < 3; ++i) Vs[i][k] = V[i][c0];
        for (int i = 0; i < 3; ++i) {
            double s = 0.0;
            for (int j = 0; j < 3; ++j) s += H[i][j] * Vs[j][k];
            U[i][k] = s * inv;
        }
    }

    double detH = H[0][0] * (H[1][1] * H[2][2] - H[1][2] * H[2][1])
                - H[0][1] * (H[1][0] * H[2][2] - H[1][2] * H[2][0])
                + H[0][2] * (H[1][0] * H[2][1] - H[1][1] * H[2][0]);
    double d = (detH < 0.0) ? -1.0 : 1.0;

    double R[3][3];
    for (int i = 0; i < 3; ++i)
        for (int j = 0; j < 3; ++j)
            R[i][j] = U[i][0] * Vs[j][0] + U[i][1] * Vs[j][1] + d * U[i][2] * Vs[j][2];

    double tv[3];
    for (int i = 0; i < 3; ++i)
        tv[i] = mu[i] - (R[i][0] * mg[0] + R[i][1] * mg[1] + R[i][2] * mg[2]);

    for (int i = 0; i < 3; ++i)
        for (int j = 0; j < 3; ++j) rt[i * 3 + j] = (float)R[i][j];
    for (int i = 0; i < 3; ++i) rt[9 + i] = (float)tv[i];
}

// ---------------- Pass 3a: apply from f16 copy (half read bytes, write-limited) ----------------
__global__ __launch_bounds__(BLK) void wra_apply_h(
    const f16x4* __restrict__ g16, const float* __restrict__ g,
    const float* __restrict__ rt, float* __restrict__ out,
    int n4, int n, int ntiles)
{
    __shared__ f16x4 ibuf[768];   // 6 KB
    __shared__ f32x4 obuf[768];   // 12 KB

    float R00 = rt[0], R01 = rt[1], R02 = rt[2];
    float R10 = rt[3], R11 = rt[4], R12 = rt[5];
    float R20 = rt[6], R21 = rt[7], R22 = rt[8];
    float t0 = rt[9], t1 = rt[10], t2 = rt[11];

    f32x4* __restrict__ o4 = (f32x4*)out;

    const int tid = threadIdx.x;
    const int totc = 3 * n4;

    for (int t = blockIdx.x; t < ntiles; t += gridDim.x) {
        const int cb = t * 768;
#pragma unroll
        for (int k = 0; k < 3; ++k) {
            int c = cb + tid + 256 * k;
            if (c < totc) ibuf[tid + 256 * k] = g16[c];
        }
        __syncthreads();

        f32x4 ga = __builtin_convertvector(ibuf[3 * tid + 0], f32x4);
        f32x4 gb = __builtin_convertvector(ibuf[3 * tid + 1], f32x4);
        f32x4 gc = __builtin_convertvector(ibuf[3 * tid + 2], f32x4);
        float qx0 = ga.x, qy0 = ga.y, qz0 = ga.z;
        float qx1 = ga.w, qy1 = gb.x, qz1 = gb.y;
        float qx2 = gb.z, qy2 = gb.w, qz2 = gc.x;
        float qx3 = gc.y, qy3 = gc.z, qz3 = gc.w;

        f32x4 r0, r1, r2;
        r0.x = R00*qx0 + R01*qy0 + R02*qz0 + t0;
        r0.y = R10*qx0 + R11*qy0 + R12*qz0 + t1;
        r0.z = R20*qx0 + R21*qy0 + R22*qz0 + t2;
        r0.w = R00*qx1 + R01*qy1 + R02*qz1 + t0;
        r1.x = R10*qx1 + R11*qy1 + R12*qz1 + t1;
        r1.y = R20*qx1 + R21*qy1 + R22*qz1 + t2;
        r1.z = R00*qx2 + R01*qy2 + R02*qz2 + t0;
        r1.w = R10*qx2 + R11*qy2 + R12*qz2 + t1;
        r2.x = R20*qx2 + R21*qy2 + R22*qz2 + t2;
        r2.y = R00*qx3 + R01*qy3 + R02*qz3 + t0;
        r2.z = R10*qx3 + R11*qy3 + R12*qz3 + t1;
        r2.w = R20*qx3 + R21*qy3 + R22*qz3 + t2;

        obuf[3 * tid + 0] = r0;
        obuf[3 * tid + 1] = r1;
        obuf[3 * tid + 2] = r2;
        __syncthreads();

#pragma unroll
        for (int k = 0; k < 3; ++k) {
            int c = cb + tid + 256 * k;
            if (c < totc) o4[c] = obuf[tid + 256 * k];
        }
        __syncthreads();   // protect ibuf/obuf reuse next tile
    }

    // scalar tail (full f32 from original g)
    int gtid = blockIdx.x * blockDim.x + threadIdx.x;
    int gstr = gridDim.x * blockDim.x;
    for (int r = n4 * 4 + gtid; r < n; r += gstr) {
        float Gx = g[3*r], Gy = g[3*r+1], Gz = g[3*r+2];
        out[3*r+0] = R00*Gx + R01*Gy + R02*Gz + t0;
        out[3*r+1] = R10*Gx + R11*Gy + R12*Gz + t1;
        out[3*r+2] = R20*Gx + R21*Gy + R22*Gz + t2;
    }
}

// ---------------- Pass 3b: fallback apply from f32 g (R2-proven) ----------------
__global__ __launch_bounds__(BLK) void wra_apply_f(
    const float* __restrict__ g, const float* __restrict__ rt,
    float* __restrict__ out, int n4, int n, int ntiles)
{
    __shared__ f32x4 buf[768];

    float R00 = rt[0], R01 = rt[1], R02 = rt[2];
    float R10 = rt[3], R11 = rt[4], R12 = rt[5];
    float R20 = rt[6], R21 = rt[7], R22 = rt[8];
    float t0 = rt[9], t1 = rt[10], t2 = rt[11];

    const f32x4* __restrict__ g4 = (const f32x4*)g;
    f32x4* __restrict__ o4 = (f32x4*)out;

    const int tid = threadIdx.x;
    const int totc = 3 * n4;

    for (int t = blockIdx.x; t < ntiles; t += gridDim.x) {
        const int cb = t * 768;
#pragma unroll
        for (int k = 0; k < 3; ++k) {
            int c = cb + tid + 256 * k;
            if (c < totc) buf[tid + 256 * k] = g4[c];
        }
        __syncthreads();

        f32x4 ga = buf[3 * tid + 0], gb = buf[3 * tid + 1], gc = buf[3 * tid + 2];
        float qx0 = ga.x, qy0 = ga.y, qz0 = ga.z;
        float qx1 = ga.w, qy1 = gb.x, qz1 = gb.y;
        float qx2 = gb.z, qy2 = gb.w, qz2 = gc.x;
        float qx3 = gc.y, qy3 = gc.z, qz3 = gc.w;

        f32x4 r0, r1, r2;
        r0.x = R00*qx0 + R01*qy0 + R02*qz0 + t0;
        r0.y = R10*qx0 + R11*qy0 + R12*qz0 + t1;
        r0.z = R20*qx0 + R21*qy0 + R22*qz0 + t2;
        r0.w = R00*qx1 + R01*qy1 + R02*qz1 + t0;
        r1.x = R10*qx1 + R11*qy1 + R12*qz1 + t1;
        r1.y = R20*qx1 + R21*qy1 + R22*qz1 + t2;
        r1.z = R00*qx2 + R01*qy2 + R02*qz2 + t0;
        r1.w = R10*qx2 + R11*qy2 + R12*qz2 + t1;
        r2.x = R20*qx2 + R21*qy2 + R22*qz2 + t2;
        r2.y = R00*qx3 + R01*qy3 + R02*qz3 + t0;
        r2.z = R10*qx3 + R11*qy3 + R12*qz3 + t1;
        r2.w = R20*qx3 + R21*qy3 + R22*qz3 + t2;

        buf[3 * tid + 0] = r0;
        buf[3 * tid + 1] = r1;
        buf[3 * tid + 2] = r2;
        __syncthreads();

#pragma unroll
        for (int k = 0; k < 3; ++k) {
            int c = cb + tid + 256 * k;
            if (c < totc) o4[c] = buf[tid + 256 * k];
        }
        __syncthreads();
    }

    int gtid = blockIdx.x * blockDim.x + threadIdx.x;
    int gstr = gridDim.x * blockDim.x;
    for (int r = n4 * 4 + gtid; r < n; r += gstr) {
        float Gx = g[3*r], Gy = g[3*r+1], Gz = g[3*r+2];
        out[3*r+0] = R00*Gx + R01*Gy + R02*Gz + t0;
        out[3*r+1] = R10*Gx + R11*Gy + R12*Gz + t1;
        out[3*r+2] = R20*Gx + R21*Gy + R22*Gz + t2;
    }
}

extern "C" void kernel_launch(void* const* d_in, const int* in_sizes, int n_in,
                              void* d_out, int out_size, void* d_ws, size_t ws_size,
                              hipStream_t stream)
{
    const float* x = (const float*)d_in[0];
    const float* g = (const float*)d_in[1];
    const float* w = (const float*)d_in[2];
    float* out = (float*)d_out;

    int n = in_sizes[2];      // number of points
    int n4 = n / 4;           // float4 groups
    int ntiles = (n4 + 255) / 256;
    if (ntiles < 1) ntiles = 1;

    // R2-proven reduce grid: 1024 persistent blocks
    int nbr = 1024;
    int maxnb = (int)((ws_size / sizeof(float) - 12) / 16);
    if (nbr > maxnb) nbr = maxnb;
    if (nbr > ntiles) nbr = ntiles;
    if (nbr < 1) nbr = 1;

    float* partials = (float*)d_ws;
    float* rt = partials + (size_t)nbr * 16;

    // f16 g copy in ws (24 MB at n=4M), 256-byte aligned
    size_t base = ((size_t)nbr * 16 + 12) * sizeof(float);
    size_t g16off = (base + 255) & ~(size_t)255;
    size_t g16bytes = (size_t)3 * (size_t)n4 * sizeof(f16x4);
    bool use16 = (n4 > 0) && (ws_size >= g16off + g16bytes);
    f16x4* g16 = use16 ? (f16x4*)((char*)d_ws + g16off) : (f16x4*)nullptr;

    wra_reduce<<<nbr, BLK, 0, stream>>>(x, g, w, partials, g16, n4, n, ntiles);
    wra_solve<<<1, 64, 0, stream>>>(partials, nbr, rt);

    int nba = ntiles < 2048 ? ntiles : 2048;
    if (use16)
        wra_apply_h<<<nba, BLK, 0, stream>>>(g16, g, rt, out, n4, n, ntiles);
    else
        wra_apply_f<<<nba, BLK, 0, stream>>>(g, rt, out, n4, n, ntiles);
}